// Round 2
// baseline (194.752 us; speedup 1.0000x reference)
//
#include <hip/hip_runtime.h>
#include <stdint.h>

typedef unsigned short u16;
typedef unsigned long long u64;
typedef __attribute__((ext_vector_type(8))) short short8;
typedef __attribute__((ext_vector_type(4))) short short4v;
typedef __attribute__((ext_vector_type(4))) float f32x4;

#define MFMA16 __builtin_amdgcn_mfma_f32_16x16x32_bf16

#define B_ 1024
#define N_ 64
#define H_ 256
#define MTOT (B_ * N_)   // 65536

__device__ __forceinline__ u16 f2bf(float f) {
  union { float f; uint32_t u; } v; v.f = f;
  uint32_t r = v.u + 0x7FFFu + ((v.u >> 16) & 1u);
  return (u16)(r >> 16);
}

union U8 { short8 v; short4v h[2]; u16 u[8]; };

// global -> LDS async copy, 16B per lane. LDS dest must be the wave-uniform
// base (HW adds lane*16); global src is per-lane.
__device__ __forceinline__ void cp16(const void* g, void* l) {
  __builtin_amdgcn_global_load_lds(
      (const __attribute__((address_space(1))) void*)g,
      (__attribute__((address_space(3))) void*)l, 16, 0, 0);
}

// ---------------------------------------------------------------------------
// wconv: fp32 -> bf16 for W1 (128*256) and W2,Wq,Wk,Wv (256*256 each).
// grid = 144 blocks x 256 thr, 8 elems/thread.
// ---------------------------------------------------------------------------
__global__ __launch_bounds__(256) void wconv(
    const float* __restrict__ W1, const float* __restrict__ W2,
    const float* __restrict__ Wq, const float* __restrict__ Wk,
    const float* __restrict__ Wv,
    u16* o1, u16* o2, u16* oq, u16* ok, u16* ov) {
  int off8 = blockIdx.x * 256 + threadIdx.x;   // index in units of 8 elems
  const float* src; u16* dst;
  if      (off8 <  4096) { src = W1; dst = o1; }
  else if (off8 < 12288) { src = W2; dst = o2; off8 -= 4096; }
  else if (off8 < 20480) { src = Wq; dst = oq; off8 -= 12288; }
  else if (off8 < 28672) { src = Wk; dst = ok; off8 -= 20480; }
  else                   { src = Wv; dst = ov; off8 -= 28672; }
  const int e = off8 * 8;
  f32x4 a = *(const f32x4*)(src + e);
  f32x4 b = *(const f32x4*)(src + e + 4);
  U8 pk;
#pragma unroll
  for (int j = 0; j < 4; j++) { pk.u[j] = f2bf(a[j]); pk.u[4 + j] = f2bf(b[j]); }
  *(short8*)(dst + e) = pk.v;
}

// ---------------------------------------------------------------------------
// prep1: M1 = Wc @ Wo (fp32), bv = bc + Wc @ bo
// ---------------------------------------------------------------------------
__global__ __launch_bounds__(256) void prep1(
    const float* __restrict__ Wc, const float* __restrict__ Wo,
    const float* __restrict__ bo, const float* __restrict__ bc,
    float* __restrict__ M1, float* __restrict__ bv) {
  const int j = blockIdx.x, d = threadIdx.x;
  __shared__ float wcr[256];
  __shared__ float red[4];
  wcr[d] = Wc[j * 256 + d];
  __syncthreads();
  float acc = 0.f;
  for (int i = 0; i < 256; i++) acc += wcr[i] * Wo[i * 256 + d];
  M1[j * 256 + d] = acc;
  float p = wcr[d] * bo[d];
  for (int off = 32; off >= 1; off >>= 1) p += __shfl_xor(p, off);
  if ((d & 63) == 0) red[d >> 6] = p;
  __syncthreads();
  if (d == 0) bv[j] = bc[j] + red[0] + red[1] + red[2] + red[3];
}

// prep2: Wz = W3 @ M1 (bf16), bz = W3 @ bv
__global__ __launch_bounds__(256) void prep2(
    const float* __restrict__ W3, const float* __restrict__ M1,
    const float* __restrict__ bv, u16* __restrict__ Wz,
    float* __restrict__ bz) {
  const int a = blockIdx.x, d = threadIdx.x;
  __shared__ float w3r[256];
  __shared__ float red[4];
  w3r[d] = W3[a * 256 + d];
  __syncthreads();
  float acc = 0.f;
  for (int j = 0; j < 256; j++) acc += w3r[j] * M1[j * 256 + d];
  Wz[a * 256 + d] = f2bf(acc);
  float p = w3r[d] * bv[d];
  for (int off = 32; off >= 1; off >>= 1) p += __shfl_xor(p, off);
  if ((d & 63) == 0) red[d >> 6] = p;
  __syncthreads();
  if (d == 0) bz[a] = red[0] + red[1] + red[2] + red[3];
}

// ---------------------------------------------------------------------------
// GEMM: C[M,256] = act(A[M,K] @ W[256,K]^T + bias) -> bf16.
// 128x256 tile (full N), BK=64, 4 waves (2 row x 2 col), 4x8 16x16x32 frags.
// B (and A when bf16) staged via global_load_lds w16, linear LDS (m97).
// Coalesced bf16 epilogue through LDS (reuses As/Bs).
// ---------------------------------------------------------------------------
template<int K, bool RELU, bool A_FP32>
__global__ __launch_bounds__(256, 2) void gemm_lds(
    const void* __restrict__ Ain, const u16* __restrict__ Wb,
    const float* __restrict__ bias, u16* __restrict__ C) {
  __shared__ char smem[49152];
  u16* As = (u16*)smem;            // 128x64 bf16 = 16 KB, linear
  u16* Bs = (u16*)(smem + 16384);  // 256x64 bf16 = 32 KB, linear
  const int tid = threadIdx.x;
  const int lane = tid & 63, wid = tid >> 6;
  const int wr = wid >> 1, wc = wid & 1;
  const int ro = lane & 15, hi = lane >> 4;
  const int m0 = blockIdx.x * 128;

  f32x4 acc[4][8];
#pragma unroll
  for (int m = 0; m < 4; m++)
#pragma unroll
    for (int n = 0; n < 8; n++) acc[m][n] = (f32x4){0.f, 0.f, 0.f, 0.f};

  for (int k0 = 0; k0 < K; k0 += 64) {
    // --- stage A (128x64) ---
    if (A_FP32) {
      const float* Af = (const float*)Ain;
#pragma unroll
      for (int it = 0; it < 4; it++) {
        const int e = (tid + it * 256) * 8;       // elem in tile
        const int r = e >> 6, c = e & 63;
        const float* s = Af + (size_t)(m0 + r) * K + k0 + c;
        f32x4 a = *(const f32x4*)s, b = *(const f32x4*)(s + 4);
        U8 pk;
#pragma unroll
        for (int j = 0; j < 4; j++) { pk.u[j] = f2bf(a[j]); pk.u[4 + j] = f2bf(b[j]); }
        *(short8*)&As[r * 64 + c] = pk.v;
      }
    } else {
      const u16* Ab = (const u16*)Ain;
#pragma unroll
      for (int i = 0; i < 4; i++) {
        const int boff = i * 4096 + wid * 1024;   // uniform byte off in tile
        const int loff = boff + lane * 16;        // per-lane byte off
        const int r = loff >> 7, cb = loff & 127;
        cp16(Ab + (size_t)(m0 + r) * K + k0 + (cb >> 1), As + (boff >> 1));
      }
    }
    // --- stage B (256x64) via global_load_lds ---
#pragma unroll
    for (int i = 0; i < 8; i++) {
      const int boff = i * 4096 + wid * 1024;
      const int loff = boff + lane * 16;
      const int r = loff >> 7, cb = loff & 127;
      cp16(Wb + (size_t)r * K + k0 + (cb >> 1), Bs + (boff >> 1));
    }
    __syncthreads();
    // --- compute ---
#pragma unroll
    for (int kk = 0; kk < 64; kk += 32) {
      short8 af[4], bfr[8];
#pragma unroll
      for (int m = 0; m < 4; m++)
        af[m] = *(const short8*)&As[(wr * 64 + m * 16 + ro) * 64 + kk + hi * 8];
#pragma unroll
      for (int n = 0; n < 8; n++)
        bfr[n] = *(const short8*)&Bs[(wc * 128 + n * 16 + ro) * 64 + kk + hi * 8];
#pragma unroll
      for (int m = 0; m < 4; m++)
#pragma unroll
        for (int n = 0; n < 8; n++)
          acc[m][n] = MFMA16(af[m], bfr[n], acc[m][n], 0, 0, 0);
    }
    __syncthreads();
  }

  // --- epilogue: bias+act+bf16, stage through LDS, coalesced store ---
  u16 (*Cs)[264] = (u16(*)[264])smem;   // 64 x 264 u16 = 33.8 KB
#pragma unroll
  for (int half = 0; half < 2; half++) {
    if (wr == half) {
#pragma unroll
      for (int n = 0; n < 8; n++) {
        const int col = wc * 128 + n * 16 + ro;
        const float bb = bias[col];
#pragma unroll
        for (int m = 0; m < 4; m++) {
#pragma unroll
          for (int j = 0; j < 4; j++) {
            float val = acc[m][n][j] + bb;
            if (RELU) val = fmaxf(val, 0.f);
            Cs[m * 16 + hi * 4 + j][col] = f2bf(val);
          }
        }
      }
    }
    __syncthreads();
    for (int i = tid; i < 64 * 32; i += 256) {
      const int r = i >> 5, c = (i & 31) << 3;
      *(short8*)(C + (size_t)(m0 + half * 64 + r) * 256 + c) = *(short8*)&Cs[r][c];
    }
    __syncthreads();
  }
}

// ---------------------------------------------------------------------------
// attn_fused: per b — QK^T, masked in-register softmax, PV, Z = O@Wz^T,
// comm out = adj@Z + b3 + deg*bz. 4 waves, wave = head.
// ---------------------------------------------------------------------------
__global__ __launch_bounds__(256) void attn_fused(
    const u16* __restrict__ Qg, const u16* __restrict__ Kg,
    const u16* __restrict__ Vg, const float* __restrict__ adj,
    const u16* __restrict__ Wz, const float* __restrict__ bz,
    const float* __restrict__ b3, float* __restrict__ out) {
  __shared__ u16 Qs[64][264];
  __shared__ u16 Ks[64][264];     // reused as zs (f32 [64][16]) in comm phase
  __shared__ u16 Vt[256][76];     // V transposed: Vt[d][k]
  __shared__ u16 Ps[4][64][76];   // P per head; reused for O per head
  __shared__ u64 adjm[64];
  __shared__ u16 chunk[64][4];

  const int b = blockIdx.x, tid = threadIdx.x;
  const int lane = tid & 63, w = tid >> 6;
  const int ro = lane & 15, hi = lane >> 4;
  const size_t base = (size_t)b * 64 * 256;
  const int hc = w * 64;

  // --- phase 1: load Q,K; transpose V; build adj bitmask chunks ---
  for (int i = tid; i < 2048; i += 256) {
    const int r = i >> 5, c = (i & 31) << 3;
    *(short8*)&Qs[r][c] = *(const short8*)(Qg + base + (size_t)r * 256 + c);
    *(short8*)&Ks[r][c] = *(const short8*)(Kg + base + (size_t)r * 256 + c);
  }
  for (int i = tid; i < 2048; i += 256) {
    const int r = i >> 5, c = (i & 31) << 3;
    U8 vv; vv.v = *(const short8*)(Vg + base + (size_t)r * 256 + c);
#pragma unroll
    for (int j = 0; j < 8; j++) {
      const int jr = (j + lane) & 7;    // per-lane rotation spreads banks
      Vt[c + jr][r] = vv.u[jr];
    }
  }
  {
    const int q = tid >> 2, qa = tid & 3;
    const float* ar = adj + ((size_t)b * 64 + q) * 64 + qa * 16;
    unsigned int m16 = 0;
#pragma unroll
    for (int i2 = 0; i2 < 16; i2++) m16 |= (unsigned)(ar[i2] != 0.f) << i2;
    chunk[q][qa] = (u16)m16;
  }
  __syncthreads();
  if (tid < 64)
    adjm[tid] = (u64)chunk[tid][0] | ((u64)chunk[tid][1] << 16) |
                ((u64)chunk[tid][2] << 32) | ((u64)chunk[tid][3] << 48);
  __syncthreads();

  // --- phase 2: S = QK^T (head w) ---
  f32x4 s[4][4];
#pragma unroll
  for (int m = 0; m < 4; m++)
#pragma unroll
    for (int n = 0; n < 4; n++) s[m][n] = (f32x4){0.f, 0.f, 0.f, 0.f};
#pragma unroll
  for (int kk = 0; kk < 64; kk += 32) {
    short8 qa_[4], kb[4];
#pragma unroll
    for (int m = 0; m < 4; m++)
      qa_[m] = *(const short8*)&Qs[m * 16 + ro][hc + kk + hi * 8];
#pragma unroll
    for (int n = 0; n < 4; n++)
      kb[n] = *(const short8*)&Ks[n * 16 + ro][hc + kk + hi * 8];
#pragma unroll
    for (int m = 0; m < 4; m++)
#pragma unroll
      for (int n = 0; n < 4; n++)
        s[m][n] = MFMA16(qa_[m], kb[n], s[m][n], 0, 0, 0);
  }

  // --- phase 3: masked softmax fully in-register (rows across ro lanes) ---
#pragma unroll
  for (int m = 0; m < 4; m++) {
#pragma unroll
    for (int j = 0; j < 4; j++) {
      const int q = m * 16 + hi * 4 + j;
      const u64 msk = adjm[q];             // broadcast within hi-group
      float sv[4], ev[4];
      float mx = -3.0e38f;
#pragma unroll
      for (int n = 0; n < 4; n++) {
        const bool on = (msk >> (n * 16 + ro)) & 1ull;
        sv[n] = on ? s[m][n][j] * 0.125f : -3.0e38f;
        mx = fmaxf(mx, sv[n]);
      }
      mx = fmaxf(mx, __shfl_xor(mx, 1));
      mx = fmaxf(mx, __shfl_xor(mx, 2));
      mx = fmaxf(mx, __shfl_xor(mx, 4));
      mx = fmaxf(mx, __shfl_xor(mx, 8));
      float sum = 0.f;
#pragma unroll
      for (int n = 0; n < 4; n++) {
        ev[n] = (sv[n] > -1.0e37f) ? __expf(sv[n] - mx) : 0.f;
        sum += ev[n];
      }
      sum += __shfl_xor(sum, 1);
      sum += __shfl_xor(sum, 2);
      sum += __shfl_xor(sum, 4);
      sum += __shfl_xor(sum, 8);
      const float inv = 1.0f / sum;
#pragma unroll
      for (int n = 0; n < 4; n++)
        Ps[w][q][n * 16 + ro] = f2bf(ev[n] * inv);
    }
  }
  // no barrier needed: each wave reads only its own Ps[w] (in-order DS)

  // --- phase 4: O = P @ V (head w), O overwrites Ps[w] ---
  {
    f32x4 o[4][4];
#pragma unroll
    for (int m = 0; m < 4; m++)
#pragma unroll
      for (int n = 0; n < 4; n++) o[m][n] = (f32x4){0.f, 0.f, 0.f, 0.f};
#pragma unroll
    for (int kk = 0; kk < 64; kk += 32) {
      U8 pa[4], vb[4];
#pragma unroll
      for (int m = 0; m < 4; m++) {
        pa[m].h[0] = *(const short4v*)&Ps[w][m * 16 + ro][kk + hi * 8];
        pa[m].h[1] = *(const short4v*)&Ps[w][m * 16 + ro][kk + hi * 8 + 4];
      }
#pragma unroll
      for (int n = 0; n < 4; n++) {
        vb[n].h[0] = *(const short4v*)&Vt[hc + n * 16 + ro][kk + hi * 8];
        vb[n].h[1] = *(const short4v*)&Vt[hc + n * 16 + ro][kk + hi * 8 + 4];
      }
#pragma unroll
      for (int m = 0; m < 4; m++)
#pragma unroll
        for (int n = 0; n < 4; n++)
          o[m][n] = MFMA16(pa[m].v, vb[n].v, o[m][n], 0, 0, 0);
    }
#pragma unroll
    for (int m = 0; m < 4; m++)
#pragma unroll
      for (int n = 0; n < 4; n++)
#pragma unroll
        for (int j = 0; j < 4; j++)
          Ps[w][m * 16 + hi * 4 + j][n * 16 + ro] = f2bf(o[m][n][j]);
  }
  __syncthreads();

  // --- phase 5: Z[64,16] = O[64,256] @ Wz[16,256]^T; wave w does rows 16w ---
  float* zsf = (float*)Ks;   // 64 x 16 f32 (Ks dead)
  {
    f32x4 z = (f32x4){0.f, 0.f, 0.f, 0.f};
#pragma unroll
    for (int kc = 0; kc < 256; kc += 32) {
      const int head = kc >> 6, koff = kc & 63;
      U8 oa;
      oa.h[0] = *(const short4v*)&Ps[head][16 * w + ro][koff + hi * 8];
      oa.h[1] = *(const short4v*)&Ps[head][16 * w + ro][koff + hi * 8 + 4];
      short8 wzb = *(const short8*)(Wz + ro * 256 + kc + hi * 8);
      z = MFMA16(oa.v, wzb, z, 0, 0, 0);
    }
#pragma unroll
    for (int j = 0; j < 4; j++)
      zsf[(16 * w + hi * 4 + j) * 16 + ro] = z[j];
  }
  __syncthreads();

  // --- phase 6: out = adj @ Z + b3 + deg*bz ---
  {
    const int n = tid >> 2, a4 = (tid & 3) << 2;
    const u64 msk = adjm[n];
    const float deg = (float)__popcll(msk);
    float a0 = 0.f, a1 = 0.f, a2 = 0.f, a3 = 0.f;
#pragma unroll 8
    for (int m = 0; m < 64; m++) {
      const float wv = (float)((msk >> m) & 1ull);
      a0 += wv * zsf[m * 16 + a4 + 0];
      a1 += wv * zsf[m * 16 + a4 + 1];
      a2 += wv * zsf[m * 16 + a4 + 2];
      a3 += wv * zsf[m * 16 + a4 + 3];
    }
    f32x4 r;
    r[0] = a0 + b3[a4 + 0] + deg * bz[a4 + 0];
    r[1] = a1 + b3[a4 + 1] + deg * bz[a4 + 1];
    r[2] = a2 + b3[a4 + 2] + deg * bz[a4 + 2];
    r[3] = a3 + b3[a4 + 3] + deg * bz[a4 + 3];
    *(f32x4*)(out + ((size_t)b * 64 + n) * 16 + a4) = r;
  }
}

// ---------------------------------------------------------------------------
extern "C" void kernel_launch(void* const* d_in, const int* in_sizes, int n_in,
                              void* d_out, int out_size, void* d_ws, size_t ws_size,
                              hipStream_t stream) {
  const float* obs = (const float*)d_in[0];
  const float* adj = (const float*)d_in[1];
  const float* W1  = (const float*)d_in[2];
  const float* b1  = (const float*)d_in[3];
  const float* W2  = (const float*)d_in[4];
  const float* b2  = (const float*)d_in[5];
  const float* Wq  = (const float*)d_in[6];
  const float* bq  = (const float*)d_in[7];
  const float* Wk  = (const float*)d_in[8];
  const float* bk  = (const float*)d_in[9];
  const float* Wv  = (const float*)d_in[10];
  const float* bvw = (const float*)d_in[11];
  const float* Wo  = (const float*)d_in[12];
  const float* bo  = (const float*)d_in[13];
  const float* Wc  = (const float*)d_in[14];
  const float* bc  = (const float*)d_in[15];
  const float* W3  = (const float*)d_in[16];
  const float* b3  = (const float*)d_in[17];
  float* out = (float*)d_out;

  char* ws = (char*)d_ws;
  const size_t BIG = (size_t)MTOT * 256 * 2;       // 33.5 MB
  u16* buf0 = (u16*)(ws);                          // x1, then q
  u16* buf1 = (u16*)(ws + BIG);                    // x2
  u16* buf2 = (u16*)(ws + 2 * BIG);                // k
  u16* buf3 = (u16*)(ws + 3 * BIG);                // v
  char* p = ws + 4 * BIG;
  u16* W1b = (u16*)p;              p += 128 * 256 * 2;
  u16* W2b = (u16*)p;              p += 256 * 256 * 2;
  u16* Wqb = (u16*)p;              p += 256 * 256 * 2;
  u16* Wkb = (u16*)p;              p += 256 * 256 * 2;
  u16* Wvb = (u16*)p;              p += 256 * 256 * 2;
  float* M1 = (float*)p;           p += 256 * 256 * 4;
  u16* Wz  = (u16*)p;              p += 16 * 256 * 2;
  float* bv = (float*)p;           p += 256 * 4;
  float* bz = (float*)p;           p += 16 * 4;

  dim3 blk(256);
  wconv<<<dim3(144), blk, 0, stream>>>(W1, W2, Wq, Wk, Wv, W1b, W2b, Wqb, Wkb, Wvb);
  prep1<<<dim3(256), blk, 0, stream>>>(Wc, Wo, bo, bc, M1, bv);
  prep2<<<dim3(16), blk, 0, stream>>>(W3, M1, bv, Wz, bz);

  gemm_lds<128, true,  true ><<<dim3(512), blk, 0, stream>>>(obs,  W1b, b1,  buf0);
  gemm_lds<256, true,  false><<<dim3(512), blk, 0, stream>>>(buf0, W2b, b2,  buf1);
  gemm_lds<256, false, false><<<dim3(512), blk, 0, stream>>>(buf1, Wqb, bq,  buf0);
  gemm_lds<256, false, false><<<dim3(512), blk, 0, stream>>>(buf1, Wkb, bk,  buf2);
  gemm_lds<256, false, false><<<dim3(512), blk, 0, stream>>>(buf1, Wvb, bvw, buf3);

  attn_fused<<<dim3(1024), blk, 0, stream>>>(buf0, buf2, buf3, adj, Wz, bz, b3, out);
}

// Round 3
// 150.691 us; speedup vs baseline: 1.2924x; 1.2924x over previous
//
#include <hip/hip_runtime.h>
#include <stdint.h>

typedef unsigned short u16;
typedef unsigned long long u64;
typedef __attribute__((ext_vector_type(8))) short short8;
typedef __attribute__((ext_vector_type(4))) float f32x4;

#define MFMA16 __builtin_amdgcn_mfma_f32_16x16x32_bf16

#define B_ 1024
#define N_ 64
#define H_ 256
#define MTOT (B_ * N_)   // 65536

__device__ __forceinline__ u16 f2bf(float f) {
  union { float f; uint32_t u; } v; v.f = f;
  uint32_t r = v.u + 0x7FFFu + ((v.u >> 16) & 1u);
  return (u16)(r >> 16);
}

union U8 { short8 v; u16 u[8]; };
union U4 { u64 v; u16 u[4]; };

__device__ __forceinline__ void cp16(const void* g, void* l) {
  __builtin_amdgcn_global_load_lds(
      (const __attribute__((address_space(1))) void*)g,
      (__attribute__((address_space(3))) void*)l, 16, 0, 0);
}

// ---------------------------------------------------------------------------
// wconv: fp32 -> bf16 weights
// ---------------------------------------------------------------------------
__global__ __launch_bounds__(256) void wconv(
    const float* __restrict__ W1, const float* __restrict__ W2,
    const float* __restrict__ Wq, const float* __restrict__ Wk,
    const float* __restrict__ Wv,
    u16* o1, u16* o2, u16* oq, u16* ok, u16* ov) {
  int off8 = blockIdx.x * 256 + threadIdx.x;
  const float* src; u16* dst;
  if      (off8 <  4096) { src = W1; dst = o1; }
  else if (off8 < 12288) { src = W2; dst = o2; off8 -= 4096; }
  else if (off8 < 20480) { src = Wq; dst = oq; off8 -= 12288; }
  else if (off8 < 28672) { src = Wk; dst = ok; off8 -= 20480; }
  else                   { src = Wv; dst = ov; off8 -= 28672; }
  const int e = off8 * 8;
  f32x4 a = *(const f32x4*)(src + e);
  f32x4 b = *(const f32x4*)(src + e + 4);
  U8 pk;
#pragma unroll
  for (int j = 0; j < 4; j++) { pk.u[j] = f2bf(a[j]); pk.u[4 + j] = f2bf(b[j]); }
  *(short8*)(dst + e) = pk.v;
}

// ---------------------------------------------------------------------------
// prep1: M1 = Wc @ Wo (fp32), bv = bc + Wc @ bo
// ---------------------------------------------------------------------------
__global__ __launch_bounds__(256) void prep1(
    const float* __restrict__ Wc, const float* __restrict__ Wo,
    const float* __restrict__ bo, const float* __restrict__ bc,
    float* __restrict__ M1, float* __restrict__ bv) {
  const int j = blockIdx.x, d = threadIdx.x;
  __shared__ float wcr[256];
  __shared__ float red[4];
  wcr[d] = Wc[j * 256 + d];
  __syncthreads();
  float acc = 0.f;
  for (int i = 0; i < 256; i++) acc += wcr[i] * Wo[i * 256 + d];
  M1[j * 256 + d] = acc;
  float p = wcr[d] * bo[d];
  for (int off = 32; off >= 1; off >>= 1) p += __shfl_xor(p, off);
  if ((d & 63) == 0) red[d >> 6] = p;
  __syncthreads();
  if (d == 0) bv[j] = bc[j] + red[0] + red[1] + red[2] + red[3];
}

// prep2: Wz = W3 @ M1 (bf16), bz = W3 @ bv
__global__ __launch_bounds__(256) void prep2(
    const float* __restrict__ W3, const float* __restrict__ M1,
    const float* __restrict__ bv, u16* __restrict__ Wz,
    float* __restrict__ bz) {
  const int a = blockIdx.x, d = threadIdx.x;
  __shared__ float w3r[256];
  __shared__ float red[4];
  w3r[d] = W3[a * 256 + d];
  __syncthreads();
  float acc = 0.f;
  for (int j = 0; j < 256; j++) acc += w3r[j] * M1[j * 256 + d];
  Wz[a * 256 + d] = f2bf(acc);
  float p = w3r[d] * bv[d];
  for (int off = 32; off >= 1; off >>= 1) p += __shfl_xor(p, off);
  if ((d & 63) == 0) red[d >> 6] = p;
  __syncthreads();
  if (d == 0) bz[a] = red[0] + red[1] + red[2] + red[3];
}

// ---------------------------------------------------------------------------
// GEMM: C[M,256] = act(A[M,K] @ W[256,K]^T + bias) -> bf16.
// 128x256 tile, BK=64, 4 waves, 4x8 frags. VT: write output transposed
// per-b ([b][d][k]) directly from accumulator (for the V projection).
// ---------------------------------------------------------------------------
template<int K, bool RELU, bool A_FP32, bool VTR>
__global__ __launch_bounds__(256, 2) void gemm_lds(
    const void* __restrict__ Ain, const u16* __restrict__ Wb,
    const float* __restrict__ bias, u16* __restrict__ C) {
  __shared__ char smem[49152];
  u16* As = (u16*)smem;            // 128x64 bf16, linear
  u16* Bs = (u16*)(smem + 16384);  // 256x64 bf16, linear
  const int tid = threadIdx.x;
  const int lane = tid & 63, wid = tid >> 6;
  const int wr = wid >> 1, wc = wid & 1;
  const int ro = lane & 15, hi = lane >> 4;
  const int m0 = blockIdx.x * 128;

  f32x4 acc[4][8];
#pragma unroll
  for (int m = 0; m < 4; m++)
#pragma unroll
    for (int n = 0; n < 8; n++) acc[m][n] = (f32x4){0.f, 0.f, 0.f, 0.f};

  for (int k0 = 0; k0 < K; k0 += 64) {
    if (A_FP32) {
      const float* Af = (const float*)Ain;
#pragma unroll
      for (int it = 0; it < 4; it++) {
        const int e = (tid + it * 256) * 8;
        const int r = e >> 6, c = e & 63;
        const float* s = Af + (size_t)(m0 + r) * K + k0 + c;
        f32x4 a = *(const f32x4*)s, b = *(const f32x4*)(s + 4);
        U8 pk;
#pragma unroll
        for (int j = 0; j < 4; j++) { pk.u[j] = f2bf(a[j]); pk.u[4 + j] = f2bf(b[j]); }
        *(short8*)&As[r * 64 + c] = pk.v;
      }
    } else {
      const u16* Ab = (const u16*)Ain;
#pragma unroll
      for (int i = 0; i < 4; i++) {
        const int boff = i * 4096 + wid * 1024;
        const int loff = boff + lane * 16;
        const int r = loff >> 7, cb = loff & 127;
        cp16(Ab + (size_t)(m0 + r) * K + k0 + (cb >> 1), As + (boff >> 1));
      }
    }
#pragma unroll
    for (int i = 0; i < 8; i++) {
      const int boff = i * 4096 + wid * 1024;
      const int loff = boff + lane * 16;
      const int r = loff >> 7, cb = loff & 127;
      cp16(Wb + (size_t)r * K + k0 + (cb >> 1), Bs + (boff >> 1));
    }
    __syncthreads();
#pragma unroll
    for (int kk = 0; kk < 64; kk += 32) {
      short8 af[4], bfr[8];
#pragma unroll
      for (int m = 0; m < 4; m++)
        af[m] = *(const short8*)&As[(wr * 64 + m * 16 + ro) * 64 + kk + hi * 8];
#pragma unroll
      for (int n = 0; n < 8; n++)
        bfr[n] = *(const short8*)&Bs[(wc * 128 + n * 16 + ro) * 64 + kk + hi * 8];
#pragma unroll
      for (int m = 0; m < 4; m++)
#pragma unroll
        for (int n = 0; n < 8; n++)
          acc[m][n] = MFMA16(af[m], bfr[n], acc[m][n], 0, 0, 0);
    }
    __syncthreads();
  }

  if (VTR) {
    // transposed per-b store: Vt[b][d][k], k contiguous (4 bf16 = u64)
    const int bidx = (m0 >> 6) + wr;
#pragma unroll
    for (int n = 0; n < 8; n++) {
      const int d = wc * 128 + n * 16 + ro;
      const float bb = bias[d];
#pragma unroll
      for (int m = 0; m < 4; m++) {
        U4 pk;
#pragma unroll
        for (int j = 0; j < 4; j++) {
          float val = acc[m][n][j] + bb;
          pk.u[j] = f2bf(val);
        }
        *(u64*)(C + (size_t)bidx * 16384 + (size_t)d * 64 + m * 16 + hi * 4) = pk.v;
      }
    }
  } else {
    u16 (*Cs)[264] = (u16(*)[264])smem;
#pragma unroll
    for (int half = 0; half < 2; half++) {
      if (wr == half) {
#pragma unroll
        for (int n = 0; n < 8; n++) {
          const int col = wc * 128 + n * 16 + ro;
          const float bb = bias[col];
#pragma unroll
          for (int m = 0; m < 4; m++) {
#pragma unroll
            for (int j = 0; j < 4; j++) {
              float val = acc[m][n][j] + bb;
              if (RELU) val = fmaxf(val, 0.f);
              Cs[m * 16 + hi * 4 + j][col] = f2bf(val);
            }
          }
        }
      }
      __syncthreads();
      for (int i = tid; i < 64 * 32; i += 256) {
        const int r = i >> 5, c = (i & 31) << 3;
        *(short8*)(C + (size_t)(m0 + half * 64 + r) * 256 + c) = *(short8*)&Cs[r][c];
      }
      __syncthreads();
    }
  }
}

// ---------------------------------------------------------------------------
// attn_fused: per b. Q/K/V frags direct from global (V pre-transposed).
// LDS: P/O per head (36KB) + Z (4KB) + adj mask (1KB).
// ---------------------------------------------------------------------------
__global__ __launch_bounds__(256, 2) void attn_fused(
    const u16* __restrict__ Qg, const u16* __restrict__ Kg,
    const u16* __restrict__ Vt, const float* __restrict__ adj,
    const u16* __restrict__ Wz, const float* __restrict__ bz,
    const float* __restrict__ b3, float* __restrict__ out) {
  __shared__ u16 Ps[4][64][72];   // P then O, per head (pitch 72: 16B-aligned rows)
  __shared__ float Zs[64][16];
  __shared__ u64 adjm[64];
  __shared__ u16 chunk[64][4];

  const int b = blockIdx.x, tid = threadIdx.x;
  const int lane = tid & 63, w = tid >> 6;
  const int ro = lane & 15, hi = lane >> 4;
  const int hc = w * 64;
  const size_t base = (size_t)b * 64 * 256;

  // K fragments (B-operand): rows n*16+ro, cols hc + ks*32 + hi*8
  short8 kb[4][2];
#pragma unroll
  for (int n = 0; n < 4; n++)
#pragma unroll
    for (int ks = 0; ks < 2; ks++)
      kb[n][ks] = *(const short8*)(Kg + base + (size_t)(n * 16 + ro) * 256 + hc + ks * 32 + hi * 8);

  // adjacency bitmask
  {
    const int q = tid >> 2, qa = tid & 3;
    const float* ar = adj + ((size_t)b * 64 + q) * 64 + qa * 16;
    f32x4 a0 = *(const f32x4*)(ar);
    f32x4 a1 = *(const f32x4*)(ar + 4);
    f32x4 a2 = *(const f32x4*)(ar + 8);
    f32x4 a3 = *(const f32x4*)(ar + 12);
    unsigned m16 = 0;
#pragma unroll
    for (int i = 0; i < 4; i++) {
      m16 |= (unsigned)(a0[i] != 0.f) << i;
      m16 |= (unsigned)(a1[i] != 0.f) << (4 + i);
      m16 |= (unsigned)(a2[i] != 0.f) << (8 + i);
      m16 |= (unsigned)(a3[i] != 0.f) << (12 + i);
    }
    chunk[q][qa] = (u16)m16;
  }

  // S = QK^T (Q frags loaded per m)
  f32x4 s[4][4];
#pragma unroll
  for (int m = 0; m < 4; m++) {
    short8 af[2];
#pragma unroll
    for (int ks = 0; ks < 2; ks++)
      af[ks] = *(const short8*)(Qg + base + (size_t)(m * 16 + ro) * 256 + hc + ks * 32 + hi * 8);
#pragma unroll
    for (int n = 0; n < 4; n++) s[m][n] = (f32x4){0.f, 0.f, 0.f, 0.f};
#pragma unroll
    for (int ks = 0; ks < 2; ks++)
#pragma unroll
      for (int n = 0; n < 4; n++)
        s[m][n] = MFMA16(af[ks], kb[n][ks], s[m][n], 0, 0, 0);
  }

  // V fragments (B-operand from pre-transposed Vt): issued early to hide latency
  short8 vb[4][2];
#pragma unroll
  for (int n = 0; n < 4; n++)
#pragma unroll
    for (int ks = 0; ks < 2; ks++)
      vb[n][ks] = *(const short8*)(Vt + (size_t)b * 16384 + (size_t)(hc + n * 16 + ro) * 64 + ks * 32 + hi * 8);

  __syncthreads();   // chunk ready
  if (tid < 64)
    adjm[tid] = (u64)chunk[tid][0] | ((u64)chunk[tid][1] << 16) |
                ((u64)chunk[tid][2] << 32) | ((u64)chunk[tid][3] << 48);
  __syncthreads();

  // masked softmax in-register; write P rows to own head slot
#pragma unroll
  for (int m = 0; m < 4; m++) {
#pragma unroll
    for (int j = 0; j < 4; j++) {
      const int q = m * 16 + hi * 4 + j;
      const u64 msk = adjm[q];
      float sv[4], ev[4];
      float mx = -3.0e38f;
#pragma unroll
      for (int n = 0; n < 4; n++) {
        const bool on = (msk >> (n * 16 + ro)) & 1ull;
        sv[n] = on ? s[m][n][j] * 0.125f : -3.0e38f;
        mx = fmaxf(mx, sv[n]);
      }
      mx = fmaxf(mx, __shfl_xor(mx, 1));
      mx = fmaxf(mx, __shfl_xor(mx, 2));
      mx = fmaxf(mx, __shfl_xor(mx, 4));
      mx = fmaxf(mx, __shfl_xor(mx, 8));
      float sum = 0.f;
#pragma unroll
      for (int n = 0; n < 4; n++) {
        ev[n] = (sv[n] > -1.0e37f) ? __expf(sv[n] - mx) : 0.f;
        sum += ev[n];
      }
      sum += __shfl_xor(sum, 1);
      sum += __shfl_xor(sum, 2);
      sum += __shfl_xor(sum, 4);
      sum += __shfl_xor(sum, 8);
      const float inv = 1.0f / sum;
#pragma unroll
      for (int n = 0; n < 4; n++)
        Ps[w][q][n * 16 + ro] = f2bf(ev[n] * inv);
    }
  }
  // own-wave DS ordering: no barrier needed before reading own Ps[w]

  // O = P @ V
  f32x4 o[4][4];
#pragma unroll
  for (int m = 0; m < 4; m++) {
    short8 pa[2];
    pa[0] = *(const short8*)&Ps[w][m * 16 + ro][hi * 8];
    pa[1] = *(const short8*)&Ps[w][m * 16 + ro][32 + hi * 8];
#pragma unroll
    for (int n = 0; n < 4; n++) o[m][n] = (f32x4){0.f, 0.f, 0.f, 0.f};
#pragma unroll
    for (int ks = 0; ks < 2; ks++)
#pragma unroll
      for (int n = 0; n < 4; n++)
        o[m][n] = MFMA16(pa[ks], vb[n][ks], o[m][n], 0, 0, 0);
  }
  // O overwrites own head slot (all own reads already issued in order)
#pragma unroll
  for (int m = 0; m < 4; m++)
#pragma unroll
    for (int n = 0; n < 4; n++)
#pragma unroll
      for (int j = 0; j < 4; j++)
        Ps[w][m * 16 + hi * 4 + j][n * 16 + ro] = f2bf(o[m][n][j]);
  __syncthreads();   // all heads' O ready

  // Z rows 16w: Z[q][a] = sum over all heads of O[q][:] @ Wz[a][:]^T
  {
    f32x4 za = (f32x4){0.f, 0.f, 0.f, 0.f};
#pragma unroll
    for (int head = 0; head < 4; head++) {
#pragma unroll
      for (int ks = 0; ks < 2; ks++) {
        short8 oa = *(const short8*)&Ps[head][w * 16 + ro][ks * 32 + hi * 8];
        short8 wzb = *(const short8*)(Wz + ro * 256 + head * 64 + ks * 32 + hi * 8);
        za = MFMA16(oa, wzb, za, 0, 0, 0);
      }
    }
#pragma unroll
    for (int j = 0; j < 4; j++)
      Zs[w * 16 + hi * 4 + j][ro] = za[j];
  }
  __syncthreads();

  // out = adj @ Z + b3 + deg*bz
  {
    const int n = tid >> 2, a4 = (tid & 3) << 2;
    const u64 msk = adjm[n];
    const float deg = (float)__popcll(msk);
    float a0 = 0.f, a1 = 0.f, a2 = 0.f, a3 = 0.f;
#pragma unroll 8
    for (int m = 0; m < 64; m++) {
      const float wv = (float)((msk >> m) & 1ull);
      f32x4 z = *(const f32x4*)&Zs[m][a4];
      a0 += wv * z[0]; a1 += wv * z[1]; a2 += wv * z[2]; a3 += wv * z[3];
    }
    f32x4 r;
    r[0] = a0 + b3[a4 + 0] + deg * bz[a4 + 0];
    r[1] = a1 + b3[a4 + 1] + deg * bz[a4 + 1];
    r[2] = a2 + b3[a4 + 2] + deg * bz[a4 + 2];
    r[3] = a3 + b3[a4 + 3] + deg * bz[a4 + 3];
    *(f32x4*)(out + ((size_t)b * 64 + n) * 16 + a4) = r;
  }
}

// ---------------------------------------------------------------------------
extern "C" void kernel_launch(void* const* d_in, const int* in_sizes, int n_in,
                              void* d_out, int out_size, void* d_ws, size_t ws_size,
                              hipStream_t stream) {
  const float* obs = (const float*)d_in[0];
  const float* adj = (const float*)d_in[1];
  const float* W1  = (const float*)d_in[2];
  const float* b1  = (const float*)d_in[3];
  const float* W2  = (const float*)d_in[4];
  const float* b2  = (const float*)d_in[5];
  const float* Wq  = (const float*)d_in[6];
  const float* bq  = (const float*)d_in[7];
  const float* Wk  = (const float*)d_in[8];
  const float* bk  = (const float*)d_in[9];
  const float* Wv  = (const float*)d_in[10];
  const float* bvw = (const float*)d_in[11];
  const float* Wo  = (const float*)d_in[12];
  const float* bo  = (const float*)d_in[13];
  const float* Wc  = (const float*)d_in[14];
  const float* bc  = (const float*)d_in[15];
  const float* W3  = (const float*)d_in[16];
  const float* b3  = (const float*)d_in[17];
  float* out = (float*)d_out;

  char* ws = (char*)d_ws;
  const size_t BIG = (size_t)MTOT * 256 * 2;       // 33.5 MB
  u16* buf0 = (u16*)(ws);                          // x1, then q
  u16* buf1 = (u16*)(ws + BIG);                    // x2
  u16* buf2 = (u16*)(ws + 2 * BIG);                // k
  u16* buf3 = (u16*)(ws + 3 * BIG);                // v (transposed per b)
  char* p = ws + 4 * BIG;
  u16* W1b = (u16*)p;              p += 128 * 256 * 2;
  u16* W2b = (u16*)p;              p += 256 * 256 * 2;
  u16* Wqb = (u16*)p;              p += 256 * 256 * 2;
  u16* Wkb = (u16*)p;              p += 256 * 256 * 2;
  u16* Wvb = (u16*)p;              p += 256 * 256 * 2;
  float* M1 = (float*)p;           p += 256 * 256 * 4;
  u16* Wz  = (u16*)p;              p += 16 * 256 * 2;
  float* bv = (float*)p;           p += 256 * 4;
  float* bz = (float*)p;           p += 16 * 4;

  dim3 blk(256);
  wconv<<<dim3(144), blk, 0, stream>>>(W1, W2, Wq, Wk, Wv, W1b, W2b, Wqb, Wkb, Wvb);
  prep1<<<dim3(256), blk, 0, stream>>>(Wc, Wo, bo, bc, M1, bv);
  prep2<<<dim3(16), blk, 0, stream>>>(W3, M1, bv, Wz, bz);

  gemm_lds<128, true,  true,  false><<<dim3(512), blk, 0, stream>>>(obs,  W1b, b1,  buf0);
  gemm_lds<256, true,  false, false><<<dim3(512), blk, 0, stream>>>(buf0, W2b, b2,  buf1);
  gemm_lds<256, false, false, false><<<dim3(512), blk, 0, stream>>>(buf1, Wqb, bq,  buf0);
  gemm_lds<256, false, false, false><<<dim3(512), blk, 0, stream>>>(buf1, Wkb, bk,  buf2);
  gemm_lds<256, false, false, true ><<<dim3(512), blk, 0, stream>>>(buf1, Wvb, bvw, buf3);

  attn_fused<<<dim3(1024), blk, 0, stream>>>(buf0, buf2, buf3, adj, Wz, bz, b3, out);
}